// Round 8
// baseline (257.013 us; speedup 1.0000x reference)
//
#include <hip/hip_runtime.h>
#include <hip/hip_fp16.h>

#define BB 8
#define LL 1024
#define DIN 256
#define DM 512
#define HH 8
#define DH 64

typedef __attribute__((ext_vector_type(8))) short bf16x8;
typedef __attribute__((ext_vector_type(4))) float f32x4;

__device__ __forceinline__ unsigned short f2bf(float f) {
  union { float f; unsigned u; } c; c.f = f;
  unsigned u = c.u;
  return (unsigned short)((u + 0x7fffu + ((u >> 16) & 1u)) >> 16);
}

#if defined(__has_builtin)
#if __has_builtin(__builtin_amdgcn_cvt_pk_bf16_f32)
#define HAS_PK_BF16 1
#endif
#endif

#ifdef HAS_PK_BF16
typedef __bf16 bf2 __attribute__((ext_vector_type(2)));
__device__ __forceinline__ unsigned pk2(float lo, float hi) {
  union { bf2 v; unsigned u; } c;
  c.v = __builtin_amdgcn_cvt_pk_bf16_f32(lo, hi);
  return c.u;
}
#else
__device__ __forceinline__ unsigned pk2(float lo, float hi) {
  return ((unsigned)f2bf(hi) << 16) | f2bf(lo);
}
#endif

__device__ __forceinline__ unsigned pkh(float a, float d) {
  return (unsigned)__half_as_ushort(__float2half_rn(a)) |
         ((unsigned)__half_as_ushort(__float2half_rn(d)) << 16);
}

// 8 f32 -> bf16x8 fragment
__device__ __forceinline__ bf16x8 cvt8(f32x4 c0, f32x4 c1) {
  union { unsigned u[4]; bf16x8 v; } r;
  r.u[0] = pk2(c0[0], c0[1]); r.u[1] = pk2(c0[2], c0[3]);
  r.u[2] = pk2(c1[0], c1[1]); r.u[3] = pk2(c1[2], c1[3]);
  return r.v;
}

// async global -> LDS DMA, 16 B/lane; LDS dest = wave-uniform base + lane*16
__device__ __forceinline__ void async_copy16(void* lds, const void* g) {
  __builtin_amdgcn_global_load_lds(
      (const __attribute__((address_space(1))) unsigned*)g,
      (__attribute__((address_space(3))) unsigned*)lds, 16, 0, 0);
}

// ---------------- K1: fused bias-pack + QKV projection (f32-direct) --------
// blocks [0,8192): stream (adj,dis) -> packed fp16 pairs.
// blocks [8192,9728): qkv GEMM, f32 inputs staged via DMA, cvt after ds_read.
__global__ __launch_bounds__(256) void k1(
    const float* __restrict__ qin, const float* __restrict__ kin,
    const float* __restrict__ vin,
    const float* __restrict__ wq, const float* __restrict__ wk,
    const float* __restrict__ wv,
    const float* __restrict__ adj, const float* __restrict__ dis,
    unsigned short* __restrict__ qb, unsigned short* __restrict__ kb,
    unsigned short* __restrict__ vt, unsigned* __restrict__ bp)
{
  // arena: A 2x16384 (f32 128x32) | B 2x8192 (f32 64x32) = 49152 B
  __shared__ __align__(16) char arena[49152];
  int bx = blockIdx.x;
  if (bx < 8192) {  // ---- bias pack ----
    int t = bx * 256 + threadIdx.x;
    float4 a4 = ((const float4*)adj)[t];
    float4 d4 = ((const float4*)dis)[t];
    uint4 o = { pkh(a4.x, d4.x), pkh(a4.y, d4.y),
                pkh(a4.z, d4.z), pkh(a4.w, d4.w) };
    ((uint4*)bp)[t] = o;
    return;
  }
  bx -= 8192;
  const int t = bx >> 9;          // tensor
  const int r_ = bx & 511;
  const int m0 = (r_ >> 3) * 128;
  const int h  = r_ & 7;
  const float* __restrict__ X = (t == 0) ? qin : (t == 1) ? kin : vin;
  const float* __restrict__ W = (t == 0) ? wq : (t == 1) ? wk : wv;
  const int tid = threadIdx.x;
  const int wid = tid >> 6;
  const int lane = tid & 63;
  const int lo = lane & 15;
  const int quad = lane >> 4;
  const int r8 = lane >> 3, c8 = lane & 7;

  f32x4 acc[2][4];
#pragma unroll
  for (int mi = 0; mi < 2; ++mi)
#pragma unroll
    for (int ni = 0; ni < 4; ++ni) acc[mi][ni] = (f32x4)0.0f;

  // stage iter 0 -> parity 0 (rows 128B = 8 chunks of 4 f32, XOR-swizzled)
#pragma unroll
  for (int j = 0; j < 4; ++j)
    async_copy16(arena + j * 4096 + wid * 1024,
                 X + (size_t)(m0 + j * 32 + wid * 8 + r8) * DIN + ((c8 ^ r8) * 4));
#pragma unroll
  for (int j = 0; j < 2; ++j)
    async_copy16(arena + 32768 + j * 4096 + wid * 1024,
                 W + (size_t)(h * 64 + j * 32 + wid * 8 + r8) * DIN + ((c8 ^ r8) * 4));
  __syncthreads();

  for (int it = 0; it < 8; ++it) {
    const int p = it & 1;
    if (it < 7) {
      const int kk = (it + 1) * 32, q = 1 - p;
#pragma unroll
      for (int j = 0; j < 4; ++j)
        async_copy16(arena + q * 16384 + j * 4096 + wid * 1024,
                     X + (size_t)(m0 + j * 32 + wid * 8 + r8) * DIN + kk + ((c8 ^ r8) * 4));
#pragma unroll
      for (int j = 0; j < 2; ++j)
        async_copy16(arena + 32768 + q * 8192 + j * 4096 + wid * 1024,
                     W + (size_t)(h * 64 + j * 32 + wid * 8 + r8) * DIN + kk + ((c8 ^ r8) * 4));
    }
    const float* Af = (const float*)(arena + p * 16384);
    const float* Bf = (const float*)(arena + 32768 + p * 8192);
    bf16x8 a[2], bfr[4];
#pragma unroll
    for (int mi = 0; mi < 2; ++mi) {
      int R = wid * 32 + mi * 16 + lo;
      f32x4 c0 = *(const f32x4*)&Af[R * 32 + (((quad * 2) ^ (R & 7)) * 4)];
      f32x4 c1 = *(const f32x4*)&Af[R * 32 + (((quad * 2 + 1) ^ (R & 7)) * 4)];
      a[mi] = cvt8(c0, c1);
    }
#pragma unroll
    for (int ni = 0; ni < 4; ++ni) {
      int N = ni * 16 + lo;
      f32x4 c0 = *(const f32x4*)&Bf[N * 32 + (((quad * 2) ^ (N & 7)) * 4)];
      f32x4 c1 = *(const f32x4*)&Bf[N * 32 + (((quad * 2 + 1) ^ (N & 7)) * 4)];
      bfr[ni] = cvt8(c0, c1);
    }
#pragma unroll
    for (int mi = 0; mi < 2; ++mi)
#pragma unroll
      for (int ni = 0; ni < 4; ++ni)
        acc[mi][ni] = __builtin_amdgcn_mfma_f32_16x16x32_bf16(
            a[mi], bfr[ni], acc[mi][ni], 0, 0, 0);
    __syncthreads();
  }

  const int b = m0 >> 10;
  const int lbase0 = (m0 & 1023) + wid * 32;
  if (t < 2) {
    unsigned short* dstp = (t == 0) ? qb : kb;
#pragma unroll
    for (int mi = 0; mi < 2; ++mi)
#pragma unroll
      for (int ni = 0; ni < 4; ++ni) {
        int d = ni * 16 + lo;
#pragma unroll
        for (int r = 0; r < 4; ++r) {
          int lb = lbase0 + mi * 16 + quad * 4 + r;
          dstp[((size_t)(b * HH + h) * LL + lb) * DH + d] = f2bf(acc[mi][ni][r]);
        }
      }
  } else {
#pragma unroll
    for (int mi = 0; mi < 2; ++mi)
#pragma unroll
      for (int ni = 0; ni < 4; ++ni) {
        int d = ni * 16 + lo;
        int lb = lbase0 + mi * 16 + quad * 4;
        uint2 o = { pk2(acc[mi][ni][0], acc[mi][ni][1]),
                    pk2(acc[mi][ni][2], acc[mi][ni][3]) };
        *(uint2*)&vt[((size_t)(b * HH + h) * DH + d) * LL + lb] = o;
      }
  }
}

// ---------------- K2: fused biased attention, 3 blocks/CU pipeline ----------
// grid 1024: idx = qt*32 + hg*8 + b (XCD swizzle). 4 waves:
// (h = hg*2 + wid&1, kh = wid>>1). Single-buffered K (mid-loop raw barrier
// makes the overwrite safe), double-buffered packed bias, per-wave pbuf.
// LDS 41984 B -> 3 blocks/CU.
__global__ __launch_bounds__(256) void attn(
    const unsigned short* __restrict__ qb, const unsigned short* __restrict__ kb,
    const unsigned short* __restrict__ vt,
    const int* __restrict__ msk, const unsigned* __restrict__ bp,
    const float* __restrict__ la_, const float* __restrict__ ld_,
    unsigned short* __restrict__ ao)
{
  const int bi = blockIdx.x;
  const int b  = bi & 7;
  const int hg = (bi >> 3) & 3;
  const int q0 = (bi >> 5) * 32;
  const int tid = threadIdx.x;
  const int wid = tid >> 6;
  const int lane = tid & 63;
  const int lo = lane & 15;
  const int quad = lane >> 4;
  const int h  = hg * 2 + (wid & 1);
  const int kh = wid >> 1;
  const int bh = b * HH + h;

  // kbuf 16384 | bbuf 2x8192 | pbuf 4x2304 = 41984 B
  __shared__ __align__(16) char arena[41984];
  unsigned short* kbufw = (unsigned short*)(arena) + wid * 2048;
  unsigned short* pbufw = (unsigned short*)(arena + 32768) + wid * 1152;
  float*          mgbuf = (float*)arena;  // merge alias (post-loop)

  const float LOG2E = 1.44269504f;
  const float la2 = la_[h] * LOG2E, ld2 = ld_[h] * LOG2E;
  const float sc2 = 0.125f * LOG2E;

  const unsigned short* qp = qb + ((size_t)bh * LL + q0) * DH;
  bf16x8 qB[2][2];
#pragma unroll
  for (int nj = 0; nj < 2; ++nj)
#pragma unroll
    for (int ki = 0; ki < 2; ++ki)
      qB[nj][ki] = *(const bf16x8*)&qp[(nj * 16 + lo) * DH + ki * 32 + quad * 8];

  const unsigned short* kp = kb + (size_t)bh * LL * DH;
  const unsigned short* vp = vt + (size_t)bh * DH * LL;
  const unsigned* bpp = bp + ((size_t)b * LL + q0) * LL;
  const int* mp = msk + b * LL;

  f32x4 o[4][2];
  float rs[2] = {0.0f, 0.0f};
#pragma unroll
  for (int md = 0; md < 4; ++md)
#pragma unroll
    for (int nj = 0; nj < 2; ++nj) o[md][nj] = (f32x4)0.0f;

  const int kbeg = kh * (LL / 2);
  const int r8 = lane >> 3, p8 = lane & 7;

  // prologue: stage K tile0 (single buf) + bias tile0 (parity 0)
  {
    const unsigned short* kg = kp + (size_t)kbeg * DH;
#pragma unroll
    for (int j = 0; j < 4; ++j)
      async_copy16(arena + wid * 4096 + j * 1024,
                   kg + (j * 8 + r8) * 64 + ((p8 ^ r8) * 8));
    if ((wid & 1) == 0) {
      const int khs = wid >> 1;
      const unsigned* bg = bpp + khs * (LL / 2);
#pragma unroll
      for (int j = 0; j < 4; ++j)
        async_copy16(arena + 16384 + khs * 4096 + j * 1024,
                     bg + (size_t)(j * 8 + r8) * LL + ((p8 ^ r8) * 4));
    }
  }
  __syncthreads();

  for (int jt = 0; jt < 16; ++jt) {
    const int p = jt & 1;
    const int k0 = kbeg + jt * 32;

    // V + mask direct to VGPR (consumed later -> natural prefetch)
    bf16x8 vA[4];
#pragma unroll
    for (int md = 0; md < 4; ++md)
      vA[md] = *(const bf16x8*)&vp[(md * 16 + lo) * LL + k0 + quad * 8];
    int4 mv[2];
#pragma unroll
    for (int mi = 0; mi < 2; ++mi)
      mv[mi] = *(const int4*)&mp[k0 + mi * 16 + quad * 4];

    // ---- consume K (single buffer) ----
    bf16x8 kA[2][2];
#pragma unroll
    for (int mi = 0; mi < 2; ++mi)
#pragma unroll
      for (int ki = 0; ki < 2; ++ki)
        kA[mi][ki] = *(const bf16x8*)&kbufw[(mi * 16 + lo) * 64 +
                                            (((ki * 4 + quad) ^ (lo & 7)) * 8)];
    f32x4 s[2][2];
#pragma unroll
    for (int mi = 0; mi < 2; ++mi)
#pragma unroll
      for (int nj = 0; nj < 2; ++nj) s[mi][nj] = (f32x4)0.0f;
#pragma unroll
    for (int ki = 0; ki < 2; ++ki)
#pragma unroll
      for (int mi = 0; mi < 2; ++mi)
#pragma unroll
        for (int nj = 0; nj < 2; ++nj)
          s[mi][nj] = __builtin_amdgcn_mfma_f32_16x16x32_bf16(
              kA[mi][ki], qB[nj][ki], s[mi][nj], 0, 0, 0);

    // all waves done reading kbuf -> safe to overwrite
    asm volatile("s_waitcnt lgkmcnt(0)\n\ts_barrier" ::: "memory");

    if (jt < 15) {  // K prefetch for jt+1 into the single kbuf
      const unsigned short* kg = kp + (size_t)(k0 + 32) * DH;
#pragma unroll
      for (int j = 0; j < 4; ++j)
        async_copy16(arena + wid * 4096 + j * 1024,
                     kg + (j * 8 + r8) * 64 + ((p8 ^ r8) * 8));
    }

    // ---- bias consume (parity p) + exp + pbuf ----
    const unsigned* bbp = (const unsigned*)(arena + 16384 + p * 8192) + kh * 1024;
    float msvf[2][4];
#pragma unroll
    for (int mi = 0; mi < 2; ++mi)
#pragma unroll
      for (int r = 0; r < 4; ++r)
        msvf[mi][r] = ((&mv[mi].x)[r] != 0) ? 0.0f : -30000.0f;
#pragma unroll
    for (int mi = 0; mi < 2; ++mi)
#pragma unroll
      for (int nj = 0; nj < 2; ++nj) {
        uint4 u = *(const uint4*)&bbp[(nj * 16 + lo) * 32 +
                                      (((mi * 4 + quad) ^ (lo & 7)) * 4)];
        float p4[4];
#pragma unroll
        for (int r = 0; r < 4; ++r) {
          union { unsigned v; __half2 hh; } c; c.v = u[r];
          float tt = fmaf(__high2float(c.hh), ld2, msvf[mi][r]);
          tt = fmaf(__low2float(c.hh), la2, tt);
          p4[r] = __builtin_amdgcn_exp2f(fmaf(s[mi][nj][r], sc2, tt));
        }
        rs[nj] += (p4[0] + p4[1]) + (p4[2] + p4[3]);
        uint2 w = { pk2(p4[0], p4[1]), pk2(p4[2], p4[3]) };
        *(uint2*)&pbufw[(nj * 16 + lo) * 36 + mi * 16 + quad * 4] = w;
      }

    if (jt < 15 && (wid & 1) == 0) {  // bias prefetch into parity 1-p
      const int khs = wid >> 1;
      const unsigned* bg = bpp + khs * (LL / 2) + (jt + 1) * 32;
#pragma unroll
      for (int j = 0; j < 4; ++j)
        async_copy16(arena + 16384 + (1 - p) * 8192 + khs * 4096 + j * 1024,
                     bg + (size_t)(j * 8 + r8) * LL + ((p8 ^ r8) * 4));
    }

    asm volatile("s_waitcnt lgkmcnt(0)" ::: "memory");  // P roundtrip drain

    bf16x8 pB[2];
#pragma unroll
    for (int nj = 0; nj < 2; ++nj)
      pB[nj] = *(const bf16x8*)&pbufw[(nj * 16 + lo) * 36 + quad * 8];

#pragma unroll
    for (int md = 0; md < 4; ++md)
#pragma unroll
      for (int nj = 0; nj < 2; ++nj)
        o[md][nj] = __builtin_amdgcn_mfma_f32_16x16x32_bf16(
            vA[md], pB[nj], o[md][nj], 0, 0, 0);

    __syncthreads();  // drains K/bias DMA for jt+1; parity flip safe
  }

  // merge the two K-halves (mgbuf aliases stage buffers, dead now)
  const int hs = wid & 1;
  if (kh == 1) {
#pragma unroll
    for (int md = 0; md < 4; ++md)
#pragma unroll
      for (int nj = 0; nj < 2; ++nj)
#pragma unroll
        for (int r = 0; r < 4; ++r)
          mgbuf[hs * 2176 + ((md * 2 + nj) * 4 + r) * 64 + lane] = o[md][nj][r];
    mgbuf[hs * 2176 + 32 * 64 + lane] = rs[0];
    mgbuf[hs * 2176 + 33 * 64 + lane] = rs[1];
  }
  __syncthreads();
  if (kh == 0) {
#pragma unroll
    for (int md = 0; md < 4; ++md)
#pragma unroll
      for (int nj = 0; nj < 2; ++nj)
#pragma unroll
        for (int r = 0; r < 4; ++r)
          o[md][nj][r] += mgbuf[hs * 2176 + ((md * 2 + nj) * 4 + r) * 64 + lane];
    rs[0] += mgbuf[hs * 2176 + 32 * 64 + lane];
    rs[1] += mgbuf[hs * 2176 + 33 * 64 + lane];
    float inv[2];
#pragma unroll
    for (int nj = 0; nj < 2; ++nj) {
      rs[nj] += __shfl_xor(rs[nj], 16);
      rs[nj] += __shfl_xor(rs[nj], 32);
      inv[nj] = __builtin_amdgcn_rcpf(rs[nj]);
    }
#pragma unroll
    for (int md = 0; md < 4; ++md)
#pragma unroll
      for (int nj = 0; nj < 2; ++nj) {
        int l = q0 + nj * 16 + lo;
        uint2 st = { pk2(o[md][nj][0] * inv[nj], o[md][nj][1] * inv[nj]),
                     pk2(o[md][nj][2] * inv[nj], o[md][nj][3] * inv[nj]) };
        *(uint2*)&ao[((size_t)b * LL + l) * DM + h * DH + md * 16 + quad * 4] = st;
      }
  }
}

// ---------------- K3: output projection (W_o f32-direct) ----------------
// grid (8 ntile, 64 mtile), block 256. A = ao bf16 DMA, B = wo f32 DMA + cvt.
__global__ __launch_bounds__(256) void oproj(
    const unsigned short* __restrict__ ao, const float* __restrict__ wo,
    float* __restrict__ out)
{
  const int m0 = blockIdx.y * 128;
  const int n0 = blockIdx.x * 64;
  // A 2x8192 (bf16 128x32) | B 2x8192 (f32 64x32) = 32768 B
  __shared__ __align__(16) char arena[32768];
  const int tid = threadIdx.x;
  const int wid = tid >> 6;
  const int lane = tid & 63;
  const int lo = lane & 15;
  const int quad = lane >> 4;
  const int r8 = lane >> 3, c8 = lane & 7;
  const int r4 = lane >> 2, c4 = lane & 3;

  f32x4 acc[2][4];
#pragma unroll
  for (int mi = 0; mi < 2; ++mi)
#pragma unroll
    for (int ni = 0; ni < 4; ++ni) acc[mi][ni] = (f32x4)0.0f;

  // stage iter 0 -> parity 0
#pragma unroll
  for (int j = 0; j < 2; ++j)
    async_copy16(arena + j * 4096 + wid * 1024,
                 ao + (size_t)(m0 + j * 64 + wid * 16 + r4) * DM + ((c4 ^ (r4 & 3)) * 8));
#pragma unroll
  for (int j = 0; j < 2; ++j)
    async_copy16(arena + 16384 + j * 4096 + wid * 1024,
                 wo + (size_t)(n0 + j * 32 + wid * 8 + r8) * DM + ((c8 ^ r8) * 4));
  __syncthreads();

  for (int it = 0; it < 16; ++it) {
    const int p = it & 1;
    if (it < 15) {
      const int kk = (it + 1) * 32, q = 1 - p;
#pragma unroll
      for (int j = 0; j < 2; ++j)
        async_copy16(arena + q * 8192 + j * 4096 + wid * 1024,
                     ao + (size_t)(m0 + j * 64 + wid * 16 + r4) * DM + kk + ((c4 ^ (r4 & 3)) * 8));
#pragma unroll
      for (int j = 0; j < 2; ++j)
        async_copy16(arena + 16384 + q * 8192 + j * 4096 + wid * 1024,
                     wo + (size_t)(n0 + j * 32 + wid * 8 + r8) * DM + kk + ((c8 ^ r8) * 4));
    }
    const unsigned short* Ab = (const unsigned short*)(arena + p * 8192);
    const float* Bf = (const float*)(arena + 16384 + p * 8192);
    bf16x8 a[2], bfr[4];
#pragma unroll
    for (int mi = 0; mi < 2; ++mi) {
      int R = wid * 32 + mi * 16 + lo;
      a[mi] = *(const bf16x8*)&Ab[R * 32 + ((quad ^ (R & 3)) * 8)];
    }
#pragma unroll
    for (int ni = 0; ni < 4; ++ni) {
      int N = ni * 16 + lo;
      f32x4 c0 = *(const f32x4*)&Bf[N * 32 + (((quad * 2) ^ (N & 7)) * 4)];
      f32x4 c1 = *(const f32x4*)&Bf[N * 32 + (((quad * 2 + 1) ^ (N & 7)) * 4)];
      bfr[ni] = cvt8(c0, c1);
    }
#pragma unroll
    for (int mi = 0; mi < 2; ++mi)
#pragma unroll
      for (int ni = 0; ni < 4; ++ni)
        acc[mi][ni] = __builtin_amdgcn_mfma_f32_16x16x32_bf16(
            a[mi], bfr[ni], acc[mi][ni], 0, 0, 0);
    __syncthreads();
  }

#pragma unroll
  for (int mi = 0; mi < 2; ++mi)
#pragma unroll
    for (int ni = 0; ni < 4; ++ni)
#pragma unroll
      for (int r = 0; r < 4; ++r)
        out[(size_t)(m0 + wid * 32 + mi * 16 + quad * 4 + r) * DM +
            n0 + ni * 16 + lo] = acc[mi][ni][r];
}

extern "C" void kernel_launch(void* const* d_in, const int* in_sizes, int n_in,
                              void* d_out, int out_size, void* d_ws, size_t ws_size,
                              hipStream_t stream) {
  const float* qin = (const float*)d_in[0];
  const float* kin = (const float*)d_in[1];
  const float* vin = (const float*)d_in[2];
  const int*   msk = (const int*)d_in[3];
  const float* adj = (const float*)d_in[4];
  const float* dis = (const float*)d_in[5];
  const float* wq  = (const float*)d_in[6];
  const float* wk  = (const float*)d_in[7];
  const float* wv  = (const float*)d_in[8];
  const float* wo  = (const float*)d_in[9];
  const float* la  = (const float*)d_in[10];
  const float* ld  = (const float*)d_in[11];
  float* out = (float*)d_out;

  const size_t tensb = (size_t)BB * HH * LL * DH;   // 4,194,304 elems
  unsigned short* qb  = (unsigned short*)d_ws;
  unsigned short* kb  = qb + tensb;
  unsigned short* vt  = kb + tensb;
  unsigned short* ao  = vt + tensb;                 // (B,L,512) bf16
  unsigned*       bpk = (unsigned*)(ao + tensb);    // 33.5 MB packed bias

  k1<<<dim3(9728), 256, 0, stream>>>(qin, kin, vin, wq, wk, wv, adj, dis,
                                     qb, kb, vt, bpk);
  attn<<<dim3(1024), 256, 0, stream>>>(qb, kb, vt, msk, bpk, la, ld, ao);
  oproj<<<dim3(8, 64), 256, 0, stream>>>(ao, wo, out);
}